// Round 6
// baseline (312.182 us; speedup 1.0000x reference)
//
#include <hip/hip_runtime.h>
#include <math.h>

#ifndef M_PI
#define M_PI 3.14159265358979323846
#endif

// Shapes: x [64,1024,14,14]; w1 [256,1024]; w2 [256,256,3,3]; w3 [1024,256]
#define NB   64
#define NCOL 12544

typedef __attribute__((ext_vector_type(4))) int int4v;

// ---------------- workspace layout (float offsets) ----------------
static const size_t OF_OUT = 0;            // conv1/conv2 fp32 NHWC out [12544][256]
static const size_t OF_XC  = 3211264;      // x codes i8 NHWC [64][196][1024]
static const size_t OF_Z1P = 6422528;      // z1 codes i8 padded [64][16][16][256]
static const size_t OF_Z2C = 7471104;      // z2 codes i8 [12544][256]
static const size_t OF_WQ1 = 8273920;      // w1 codes i8 [256][1024]
static const size_t OF_WQ2 = 8339456;      // w2 codes i8 [256][9*256]
static const size_t OF_WQ3 = 8486912;      // w3 codes i8 [1024][256]
static const size_t OF_R1  = 8552448;
static const size_t OF_R2  = 8552704;
static const size_t OF_R3  = 8552960;      // 1024
static const size_t OF_T2  = 8553984;      // 256*8 tap aggregates
static const size_t OF_CXP = 8556032;      // 4 x 12544 CX partials
static const size_t OF_U2  = 8606208;      // 12544 (unpadded)
static const size_t OF_V2  = 8618752;      // 12544
static const size_t OF_CZ  = 8631296;      // 12544
static const size_t OF_P1  = 8643840;      // 196*256 x3
static const size_t OF_P2  = 8794368;      // 196*256 x3
static const size_t OF_P3  = 8944896;      // 98*1024 x3
static const size_t OF_PMM = 9245952;      // minmax partials (2560)
static const size_t OF_ST  = 9248512;      // 64 misc floats (fq params + qp's)
static const size_t OF_MS  = 9248576;      // mean/sg arrays (3072)

__device__ __forceinline__ float fqv(float v, float mn, float sc) {
    float t = (v - mn) / sc;
    t = fminf(fmaxf(t, 0.0f), 255.0f);
    return rintf(t) * sc + mn;
}
// centered code (integer-valued in [-128,127])
__device__ __forceinline__ float codef(float v, float mn, float sc) {
    float t = (v - mn) / sc;
    t = fminf(fmaxf(t, 0.0f), 255.0f);
    return rintf(t) - 128.0f;
}
__device__ __forceinline__ unsigned short f2bf(float f) { return (unsigned short)(__float_as_uint(f) >> 16); }
__device__ __forceinline__ float bf2f(unsigned short u) { return __uint_as_float(((unsigned)u) << 16); }
__device__ __forceinline__ int pack4(float a, float b, float c, float d) {
    return (int)(unsigned char)(signed char)(int)a | ((int)(unsigned char)(signed char)(int)b << 8) |
           ((int)(unsigned char)(signed char)(int)c << 16) | ((int)(unsigned char)(signed char)(int)d << 24);
}
__device__ __forceinline__ void glds16(const void* g, void* l) {
    __builtin_amdgcn_global_load_lds((const __attribute__((address_space(1))) unsigned int*)g,
                                     (__attribute__((address_space(3))) unsigned int*)l, 16, 0, 0);
}

// ---------------- fused min/max over 4 tensors -> per-block partials ----------------
__global__ __launch_bounds__(256) void k_minmax_all(const float4* __restrict__ x, const float4* __restrict__ w1,
                                                    const float4* __restrict__ w2, const float4* __restrict__ w3,
                                                    float* __restrict__ Pmm) {
    int b = blockIdx.x;
    const float4* p; int lb, nb, n4, base;
    if (b < 1024)      { p = x;  lb = b;        nb = 1024; n4 = 3211264; base = 0; }
    else if (b < 1088) { p = w1; lb = b - 1024; nb = 64;   n4 = 65536;   base = 2048; }
    else if (b < 1216) { p = w2; lb = b - 1088; nb = 128;  n4 = 147456;  base = 2176; }
    else               { p = w3; lb = b - 1216; nb = 64;   n4 = 65536;   base = 2432; }
    float mn = INFINITY, mx = -INFINITY;
    for (int i = lb * 256 + threadIdx.x; i < n4; i += nb * 256) {
        float4 v = p[i];
        mn = fminf(mn, fminf(fminf(v.x, v.y), fminf(v.z, v.w)));
        mx = fmaxf(mx, fmaxf(fmaxf(v.x, v.y), fmaxf(v.z, v.w)));
    }
    for (int o = 32; o; o >>= 1) {
        mn = fminf(mn, __shfl_down(mn, o, 64));
        mx = fmaxf(mx, __shfl_down(mx, o, 64));
    }
    __shared__ float smn[4], smx[4];
    int lane = threadIdx.x & 63, w = threadIdx.x >> 6;
    if (lane == 0) { smn[w] = mn; smx[w] = mx; }
    __syncthreads();
    if (threadIdx.x == 0) {
        for (int i = 1; i < 4; i++) { mn = fminf(mn, smn[i]); mx = fmaxf(mx, smx[i]); }
        Pmm[base + lb * 2]     = mn;
        Pmm[base + lb * 2 + 1] = mx;
    }
}

// reduce minmax partials -> (mn, scale) for x,w1,w2,w3
__global__ __launch_bounds__(256) void k_fqparams2(const float* __restrict__ Pmm, float* __restrict__ sf) {
    __shared__ float sa[4], sb[4];
    int t = threadIdx.x, lane = t & 63, w = t >> 6;
    const int nbs[4]   = {1024, 64, 128, 64};
    const int bases[4] = {0, 2048, 2176, 2432};
    for (int ten = 0; ten < 4; ten++) {
        float mn = INFINITY, mx = -INFINITY;
        for (int i = t; i < nbs[ten]; i += 256) {
            mn = fminf(mn, Pmm[bases[ten] + 2 * i]);
            mx = fmaxf(mx, Pmm[bases[ten] + 2 * i + 1]);
        }
        for (int o = 32; o; o >>= 1) {
            mn = fminf(mn, __shfl_down(mn, o, 64));
            mx = fmaxf(mx, __shfl_down(mx, o, 64));
        }
        if (lane == 0) { sa[w] = mn; sb[w] = mx; }
        __syncthreads();
        if (t == 0) {
            mn = fminf(fminf(sa[0], sa[1]), fminf(sa[2], sa[3]));
            mx = fmaxf(fmaxf(sb[0], sb[1]), fmaxf(sb[2], sb[3]));
            sf[8 + 3 * ten] = mn;
            sf[9 + 3 * ten] = fmaxf((mx - mn) / 255.0f, 1e-8f);
        }
        __syncthreads();
    }
}

// ---------------- fused weight coding (w1 | w3 | w2) ----------------
__global__ __launch_bounds__(256) void k_wcode_all(const float* __restrict__ w1, const float* __restrict__ w2,
                                                   const float* __restrict__ w3, const float* __restrict__ sf,
                                                   signed char* __restrict__ wq1, signed char* __restrict__ wq2,
                                                   signed char* __restrict__ wq3,
                                                   float* __restrict__ R1, float* __restrict__ R2,
                                                   float* __restrict__ R3, float* __restrict__ T8) {
    __shared__ float sh[64];
    int b = blockIdx.x, t = threadIdx.x;
    int lane = t & 63, wv = t >> 6;
    if (b < 1280) {
        const float* w; signed char* wc; float* R; int K, co; const float* pw;
        if (b < 256) { w = w1; wc = wq1; R = R1; K = 1024; co = b; pw = sf + 11; }
        else         { w = w3; wc = wq3; R = R3; K = 256;  co = b - 256; pw = sf + 17; }
        float mn = pw[0], s = pw[1];
        float sum = 0.f;
        for (int k0 = t * 4; k0 < K; k0 += 1024) {
            float4 v = *(const float4*)&w[(size_t)co * K + k0];
            float c0 = codef(v.x, mn, s), c1 = codef(v.y, mn, s), c2 = codef(v.z, mn, s), c3 = codef(v.w, mn, s);
            *(int*)&wc[(size_t)co * K + k0] = pack4(c0, c1, c2, c3);
            sum += c0 + c1 + c2 + c3;
        }
        for (int o = 32; o; o >>= 1) sum += __shfl_down(sum, o, 64);
        if (lane == 0) sh[wv] = sum;
        __syncthreads();
        if (t == 0) R[co] = sh[0] + sh[1] + sh[2] + sh[3];
    } else {
        int co = b - 1280, ci = t;
        float mn = sf[14], s = sf[15];
        float tp[9];
#pragma unroll
        for (int p = 0; p < 9; p++) {
            float c = codef(w2[((size_t)co * 256 + ci) * 9 + p], mn, s);
            wq2[(size_t)co * 2304 + p * 256 + ci] = (signed char)(int)c;
            tp[p] = c;
        }
        float* red = sh;      // [4][9]
        float* sT = sh + 40;  // [9]
#pragma unroll
        for (int p = 0; p < 9; p++) {
            float v = tp[p];
            for (int o = 32; o; o >>= 1) v += __shfl_down(v, o, 64);
            if (lane == 0) red[wv * 9 + p] = v;
        }
        __syncthreads();
        if (ci < 9) sT[ci] = red[ci] + red[9 + ci] + red[18 + ci] + red[27 + ci];
        __syncthreads();
        if (ci == 0) {
            float T0 = sT[0], T1 = sT[1], T2 = sT[2], T3 = sT[3],
                  T5 = sT[5], T6 = sT[6], T7 = sT[7], T8v = sT[8];
            R2[co] = T0 + T1 + T2 + T3 + sT[4] + T5 + T6 + T7 + T8v;
            float* o = &T8[co * 8];
            o[0] = T0 + T1 + T2;   // top
            o[1] = T6 + T7 + T8v;  // bot
            o[2] = T0 + T3 + T6;   // left
            o[3] = T2 + T5 + T8v;  // right
            o[4] = T0; o[5] = T2; o[6] = T6; o[7] = T8v;
        }
    }
}

// ---------------- x NCHW fp32 -> NHWC i8 codes + CX slice partials (no atomics) ----------------
__global__ __launch_bounds__(256) void k_code0(const float* __restrict__ x, signed char* __restrict__ dst,
                                               const float* __restrict__ qp, float* __restrict__ CXp) {
    __shared__ unsigned short lt[28][264];
    int n = blockIdx.z, hw0 = blockIdx.x * 28, cq = blockIdx.y * 256;
    int t = threadIdx.x;
    float qmn = qp[0], qsc = qp[1];
    const float* sp = x + ((size_t)n * 1024 + cq) * 196 + hw0;
    for (int i = t; i < 7168; i += 256) {
        int c = i / 28, hw = i - c * 28;
        lt[hw][c] = f2bf(codef(sp[(size_t)c * 196 + hw], qmn, qsc));
    }
    __syncthreads();
    int lane = t & 63, wv = t >> 6;
    int c0 = lane * 4;
#pragma unroll
    for (int s = 0; s < 7; s++) {
        int i = s * 4 + wv;
        int pk = pack4(bf2f(lt[i][c0]), bf2f(lt[i][c0 + 1]), bf2f(lt[i][c0 + 2]), bf2f(lt[i][c0 + 3]));
        *(int*)&dst[((size_t)n * 196 + hw0 + i) * 1024 + cq + c0] = pk;
    }
    for (int i = wv; i < 28; i += 4) {
        float s = bf2f(lt[i][lane]) + bf2f(lt[i][lane + 64]) +
                  bf2f(lt[i][lane + 128]) + bf2f(lt[i][lane + 192]);
        for (int o = 32; o; o >>= 1) s += __shfl_down(s, o, 64);
        if (lane == 0) CXp[blockIdx.y * NCOL + n * 196 + hw0 + i] = s;
    }
}

// ---------------- NHWC elementwise norm+quant -> i8 codes + rowsum ----------------
// PAD=1: dst = z1p padded [n][16][16][256]; rowsum unpadded [j]. PAD=0: dst=[j][256].
template <int PAD>
__global__ __launch_bounds__(256) void k_codeE(const float* __restrict__ src, signed char* __restrict__ dst,
                                               const float* __restrict__ mean, const float* __restrict__ sg,
                                               const float* __restrict__ beta, const float* __restrict__ qp,
                                               float* __restrict__ rowsum) {
    int t = threadIdx.x, lane = t & 63, wv = t >> 6;
    int c4 = lane * 4;
    float4 m4 = *(const float4*)&mean[c4];
    float4 s4 = *(const float4*)&sg[c4];
    float4 b4 = *(const float4*)&beta[c4];
    float qmn = qp[0], qsc = qp[1];
#pragma unroll
    for (int r = 0; r < 4; r++) {
        int j = blockIdx.x * 16 + wv * 4 + r;
        float4 v = *(const float4*)&src[(size_t)j * 256 + c4];
        float c0 = codef((v.x - m4.x) * s4.x + b4.x, qmn, qsc);
        float c1 = codef((v.y - m4.y) * s4.y + b4.y, qmn, qsc);
        float c2 = codef((v.z - m4.z) * s4.z + b4.z, qmn, qsc);
        float c3 = codef((v.w - m4.w) * s4.w + b4.w, qmn, qsc);
        size_t di;
        if (PAD) {
            int n = j / 196, hw = j - n * 196, h = hw / 14, w = hw - (hw / 14) * 14;
            di = (((size_t)n * 16 + h + 1) * 16 + (w + 1)) * 256 + c4;
        } else di = (size_t)j * 256 + c4;
        *(int*)&dst[di] = pack4(c0, c1, c2, c3);
        float s = c0 + c1 + c2 + c3;
        for (int o = 32; o; o >>= 1) s += __shfl_down(s, o, 64);
        if (lane == 0) rowsum[j] = s;
    }
}

// V2[j] = bounds-checked 9-tap sum of unpadded U2 [n][196]
__global__ __launch_bounds__(256) void k_v2(const float* __restrict__ U, float* __restrict__ V) {
    int j = blockIdx.x * 256 + threadIdx.x;
    if (j >= NCOL) return;
    int n = j / 196, hw = j - n * 196, h = hw / 14, w = hw - (hw / 14) * 14;
    const float* u = U + (size_t)n * 196;
    float s = 0.f;
#pragma unroll
    for (int dh = -1; dh <= 1; dh++) {
        int hh = h + dh;
        if (hh < 0 || hh >= 14) continue;
#pragma unroll
        for (int dw = -1; dw <= 1; dw++) {
            int ww = w + dw;
            if (ww < 0 || ww >= 14) continue;
            s += u[hh * 14 + ww];
        }
    }
    V[j] = s;
}

// ---------------- conv1/conv2: i8 MFMA, BM=64 j, BN=64 co, BK=128, dbuf ----------------
// MODE 0: Acts=[j][K] (conv1, K=1024, Cj = 4-slice partials). MODE 1: Acts=z1p padded, K=2304, Cj=V2.
template <int MODE>
__global__ __launch_bounds__(256, 4) void k_conv12(const signed char* __restrict__ Acts,
                                                   const signed char* __restrict__ Wts,
                                                   const float* __restrict__ R, const float* __restrict__ T8,
                                                   const float* __restrict__ Cj,
                                                   const float* __restrict__ pw, const float* __restrict__ pz,
                                                   float* __restrict__ outNHWC, int K,
                                                   float* __restrict__ Ps, float* __restrict__ Pn,
                                                   float* __restrict__ Px) {
    __shared__ __align__(16) signed char As[2 * 8192];   // 2 x 64 rows x 128B
    __shared__ __align__(16) signed char Bs[2 * 8192];   // 2 x 64 rows x 128B
    __shared__ float Lst[2][64][3];
    int tid = threadIdx.x, lane = tid & 63, wave = tid >> 6;
    int wm = wave >> 1, wn = wave & 1;
    int jb = blockIdx.x * 64, cob = blockIdx.y * 64;
    int sr = tid >> 3, spos = tid & 7, sc = spos ^ (sr & 7);

    const signed char* aq[2];
#pragma unroll
    for (int q = 0; q < 2; q++) {
        int j = jb + q * 32 + sr;
        if (MODE == 0) aq[q] = Acts + (size_t)j * K + sc * 16;
        else {
            int n = j / 196, hw = j - n * 196, h = hw / 14, w = hw - (hw / 14) * 14;
            aq[q] = Acts + (((size_t)n * 16 + h) * 16 + w) * 256 + sc * 16;
        }
    }
    const signed char* bq[2];
#pragma unroll
    for (int q = 0; q < 2; q++) bq[q] = Wts + (size_t)(cob + q * 32 + sr) * K + sc * 16;

    int4v acc[2][2];
#pragma unroll
    for (int mi = 0; mi < 2; mi++)
#pragma unroll
        for (int ni = 0; ni < 2; ni++) acc[mi][ni] = (int4v)0;

    int nk = K >> 7;
    auto stage = [&](int b, int ks) {
        size_t koA;
        if (MODE == 0) koA = (size_t)ks << 7;
        else {
            int k = ks << 7;
            int p = k >> 8, kin = k & 255;
            int rr = p / 3, ss = p - 3 * rr;
            koA = (size_t)(rr * 16 + ss) * 256 + kin;
        }
#pragma unroll
        for (int q = 0; q < 2; q++)
            glds16(aq[q] + koA, &As[b * 8192 + (q * 32 + sr) * 128 + spos * 16]);
#pragma unroll
        for (int q = 0; q < 2; q++)
            glds16(bq[q] + ((size_t)ks << 7), &Bs[b * 8192 + (q * 32 + sr) * 128 + spos * 16]);
    };

    int l15 = lane & 15, kq = lane >> 4, sw = l15 & 7;
    stage(0, 0);
    for (int ks = 0; ks < nk; ks++) {
        __syncthreads();
        if (ks + 1 < nk) stage((ks + 1) & 1, ks + 1);
        int b = ks & 1;
#pragma unroll
        for (int kc = 0; kc < 2; kc++) {
            int col = ((kc * 4 + kq) ^ sw) << 4;
            int4v a[2], bb[2];
#pragma unroll
            for (int mi = 0; mi < 2; mi++)
                a[mi] = *(const int4v*)&As[b * 8192 + (wm * 32 + mi * 16 + l15) * 128 + col];
#pragma unroll
            for (int ni = 0; ni < 2; ni++)
                bb[ni] = *(const int4v*)&Bs[b * 8192 + (wn * 32 + ni * 16 + l15) * 128 + col];
#pragma unroll
            for (int mi = 0; mi < 2; mi++)
#pragma unroll
                for (int ni = 0; ni < 2; ni++)
                    acc[mi][ni] = __builtin_amdgcn_mfma_i32_16x16x64_i8(a[mi], bb[ni], acc[mi][ni], 0, 0, 0);
        }
    }

    // epilogue: value = aw*az*S + aw*bz*(R-PT) + bw*az*Cj + bw*bz*Kvalid ; NHWC store + block partial stats
    float aw = pw[1], bw = pw[0] + 128.f * pw[1];
    float az = pz[1], bz = pz[0] + 128.f * pz[1];
    float caa = aw * az, cR = aw * bz, cC = bw * az, cK = bw * bz;
    int cco[2]; float rr0[2]; float t8v[2][8];
#pragma unroll
    for (int ni = 0; ni < 2; ni++) {
        cco[ni] = cob + wn * 32 + ni * 16 + l15;
        rr0[ni] = R[cco[ni]];
        if (MODE == 1) {
#pragma unroll
            for (int p = 0; p < 8; p++) t8v[ni][p] = T8[cco[ni] * 8 + p];
        }
    }
    float ssm[2] = {0.f, 0.f}, smnv[2] = {INFINITY, INFINITY}, smxv[2] = {-INFINITY, -INFINITY};
#pragma unroll
    for (int mi = 0; mi < 2; mi++)
#pragma unroll
        for (int reg = 0; reg < 4; reg++) {
            int j = jb + wm * 32 + mi * 16 + kq * 4 + reg;
            float cj;
            if (MODE == 0) cj = Cj[j] + Cj[NCOL + j] + Cj[2 * NCOL + j] + Cj[3 * NCOL + j];
            else cj = Cj[j];
            float constterm;
            float pt = 0.f, pb = 0.f, pl = 0.f, pr = 0.f, ctl = 0.f, ctr = 0.f, cbl = 0.f, cbr = 0.f;
            if (MODE == 1) {
                int hw = j - (j / 196) * 196;
                int h = hw / 14, w = hw - (hw / 14) * 14;
                pt = (h == 0) ? 1.f : 0.f;  pb = (h == 13) ? 1.f : 0.f;
                pl = (w == 0) ? 1.f : 0.f;  pr = (w == 13) ? 1.f : 0.f;
                ctl = pt * pl; ctr = pt * pr; cbl = pb * pl; cbr = pb * pr;
                float miss = 3.f * (pt + pb + pl + pr) - (ctl + ctr + cbl + cbr);
                constterm = cK * (256.f * (9.f - miss));
            } else {
                constterm = cK * (float)K;
            }
#pragma unroll
            for (int ni = 0; ni < 2; ni++) {
                float rsum = rr0[ni];
                if (MODE == 1)
                    rsum -= pt * t8v[ni][0] + pb * t8v[ni][1] + pl * t8v[ni][2] + pr * t8v[ni][3]
                          - ctl * t8v[ni][4] - ctr * t8v[ni][5] - cbl * t8v[ni][6] - cbr * t8v[ni][7];
                float v = caa * (float)acc[mi][ni][reg] + cR * rsum + cC * cj + constterm;
                outNHWC[(size_t)j * 256 + cco[ni]] = v;
                ssm[ni] += v;
                smnv[ni] = fminf(smnv[ni], v);
                smxv[ni] = fmaxf(smxv[ni], v);
            }
        }
#pragma unroll
    for (int ni = 0; ni < 2; ni++) {
        float s = ssm[ni], mn = smnv[ni], mx = smxv[ni];
        s += __shfl_xor(s, 16, 64); s += __shfl_xor(s, 32, 64);
        mn = fminf(mn, __shfl_xor(mn, 16, 64)); mn = fminf(mn, __shfl_xor(mn, 32, 64));
        mx = fmaxf(mx, __shfl_xor(mx, 16, 64)); mx = fmaxf(mx, __shfl_xor(mx, 32, 64));
        if (kq == 0) {
            int cl = wn * 32 + ni * 16 + l15;
            Lst[wm][cl][0] = s; Lst[wm][cl][1] = mn; Lst[wm][cl][2] = mx;
        }
    }
    __syncthreads();
    if (tid < 64) {
        float s  = Lst[0][tid][0] + Lst[1][tid][0];
        float mn = fminf(Lst[0][tid][1], Lst[1][tid][1]);
        float mx = fmaxf(Lst[0][tid][2], Lst[1][tid][2]);
        int idx = blockIdx.x * 256 + cob + tid;
        Ps[idx] = s; Pn[idx] = mn; Px[idx] = mx;
    }
}

// ---------------- conv3: i8 MFMA, BM=128 j, BN=64 co, K=256 single stage ----------------
__global__ __launch_bounds__(256, 3) void k_conv3(const signed char* __restrict__ Wts,
                                                  const signed char* __restrict__ Zc,
                                                  const float* __restrict__ R, const float* __restrict__ Cj,
                                                  const float* __restrict__ pw, const float* __restrict__ pz,
                                                  float* __restrict__ out,
                                                  float* __restrict__ Ps, float* __restrict__ Pn,
                                                  float* __restrict__ Px) {
    __shared__ __align__(16) signed char As[32768];   // acts: 128 j x 256B
    __shared__ __align__(16) signed char Bs[16384];   // wts : 64 co x 256B
    __shared__ float Lst[2][64][3];
    int tid = threadIdx.x, lane = tid & 63, wave = tid >> 6;
    int wm = wave >> 1, wn = wave & 1;
    int jb = blockIdx.x * 128, cob = blockIdx.y * 64;
    int sr = tid >> 4, spos = tid & 15;
#pragma unroll
    for (int p = 0; p < 8; p++) {
        int row = p * 16 + sr;
        int cg = spos ^ (row & 7);
        glds16(Zc + (size_t)(jb + row) * 256 + cg * 16, &As[row * 256 + spos * 16]);
    }
#pragma unroll
    for (int p = 0; p < 4; p++) {
        int row = p * 16 + sr;
        int cg = spos ^ (row & 7);
        glds16(Wts + (size_t)(cob + row) * 256 + cg * 16, &Bs[row * 256 + spos * 16]);
    }
    __syncthreads();

    int4v acc[4][2];
#pragma unroll
    for (int mi = 0; mi < 4; mi++)
#pragma unroll
        for (int ni = 0; ni < 2; ni++) acc[mi][ni] = (int4v)0;

    int l15 = lane & 15, kq = lane >> 4, sw = l15 & 7;
#pragma unroll
    for (int kc = 0; kc < 4; kc++) {
        int col = ((kc * 4 + kq) ^ sw) << 4;
        int4v a[4], bb[2];
#pragma unroll
        for (int mi = 0; mi < 4; mi++)
            a[mi] = *(const int4v*)&As[(wm * 64 + mi * 16 + l15) * 256 + col];
#pragma unroll
        for (int ni = 0; ni < 2; ni++)
            bb[ni] = *(const int4v*)&Bs[(wn * 32 + ni * 16 + l15) * 256 + col];
#pragma unroll
        for (int mi = 0; mi < 4; mi++)
#pragma unroll
            for (int ni = 0; ni < 2; ni++)
                acc[mi][ni] = __builtin_amdgcn_mfma_i32_16x16x64_i8(a[mi], bb[ni], acc[mi][ni], 0, 0, 0);
    }

    float aw = pw[1], bw = pw[0] + 128.f * pw[1];
    float az = pz[1], bz = pz[0] + 128.f * pz[1];
    float caa = aw * az, cR = aw * bz, cC = bw * az, cK = bw * bz;
    int coA[2]; float rA[2];
#pragma unroll
    for (int ni = 0; ni < 2; ni++) {
        coA[ni] = cob + wn * 32 + ni * 16 + l15;
        rA[ni] = R[coA[ni]];
    }
    float ps[2] = {0.f, 0.f}, pmn[2] = {INFINITY, INFINITY}, pmx[2] = {-INFINITY, -INFINITY};
#pragma unroll
    for (int mi = 0; mi < 4; mi++) {
        int j0 = jb + wm * 64 + mi * 16 + kq * 4;
        int n = j0 / 196, hh = j0 - n * 196;
        float4 cj = *(const float4*)&Cj[j0];
#pragma unroll
        for (int ni = 0; ni < 2; ni++) {
            float base = cR * rA[ni] + cK * 256.f;
            float4 v;
            v.x = caa * (float)acc[mi][ni][0] + base + cC * cj.x;
            v.y = caa * (float)acc[mi][ni][1] + base + cC * cj.y;
            v.z = caa * (float)acc[mi][ni][2] + base + cC * cj.z;
            v.w = caa * (float)acc[mi][ni][3] + base + cC * cj.w;
            *(float4*)&out[((size_t)n * 1024 + coA[ni]) * 196 + hh] = v;
            ps[ni] += v.x + v.y + v.z + v.w;
            pmn[ni] = fminf(pmn[ni], fminf(fminf(v.x, v.y), fminf(v.z, v.w)));
            pmx[ni] = fmaxf(pmx[ni], fmaxf(fmaxf(v.x, v.y), fmaxf(v.z, v.w)));
        }
    }
#pragma unroll
    for (int ni = 0; ni < 2; ni++) {
        float s = ps[ni], mn = pmn[ni], mx = pmx[ni];
        s += __shfl_xor(s, 16, 64); s += __shfl_xor(s, 32, 64);
        mn = fminf(mn, __shfl_xor(mn, 16, 64)); mn = fminf(mn, __shfl_xor(mn, 32, 64));
        mx = fmaxf(mx, __shfl_xor(mx, 16, 64)); mx = fmaxf(mx, __shfl_xor(mx, 32, 64));
        if (kq == 0) {
            int cl = wn * 32 + ni * 16 + l15;
            Lst[wm][cl][0] = s; Lst[wm][cl][1] = mn; Lst[wm][cl][2] = mx;
        }
    }
    __syncthreads();
    if (tid < 64) {
        float s  = Lst[0][tid][0] + Lst[1][tid][0];
        float mn = fminf(Lst[0][tid][1], Lst[1][tid][1]);
        float mx = fmaxf(Lst[0][tid][2], Lst[1][tid][2]);
        int idx = blockIdx.x * 1024 + cob + tid;
        Ps[idx] = s; Pn[idx] = mn; Px[idx] = mx;
    }
}

// ---------------- merged: reduce partials over NP jb-tiles + finalize range_norm ----------------
__global__ __launch_bounds__(1024) void k_finstats(int C, int NP,
                                                   const float* __restrict__ gamma, const float* __restrict__ beta,
                                                   const float* __restrict__ Ps, const float* __restrict__ Pn,
                                                   const float* __restrict__ Px,
                                                   float* __restrict__ mean_o, float* __restrict__ sg_o,
                                                   float* __restrict__ qp, float scale_fix) {
    __shared__ float Ss[1024], Sn[1024], Sx[1024];
    __shared__ float wr1[16], wr2[16];
    int t = threadIdx.x, lane = t & 63, wv = t >> 6;
    int c, sl, stride;
    if (C == 256) { c = t & 255; sl = t >> 8; stride = 4; }
    else          { c = t;       sl = 0;      stride = 1; }
    float s = 0.f, mn = INFINITY, mx = -INFINITY;
    for (int b = sl; b < NP; b += stride) {
        int idx = b * C + c;
        s += Ps[idx]; mn = fminf(mn, Pn[idx]); mx = fmaxf(mx, Px[idx]);
    }
    Ss[t] = s; Sn[t] = mn; Sx[t] = mx;
    __syncthreads();
    // gamma min/max (block-wide)
    float gv = (t < C) ? gamma[t] : gamma[0];
    float gmn = gv, gmx = gv;
    for (int o = 32; o; o >>= 1) { gmn = fminf(gmn, __shfl_down(gmn, o, 64)); gmx = fmaxf(gmx, __shfl_down(gmx, o, 64)); }
    if (lane == 0) { wr1[wv] = gmn; wr2[wv] = gmx; }
    __syncthreads();
    if (t == 0) {
        float a = wr1[0], b2 = wr2[0];
        for (int i = 1; i < 16; i++) { a = fminf(a, wr1[i]); b2 = fmaxf(b2, wr2[i]); }
        wr1[0] = a; wr2[0] = b2;
    }
    __syncthreads();
    gmn = wr1[0]; gmx = wr2[0];
    float gsc = fmaxf((gmx - gmn) / 255.0f, 1e-8f);
    float qmn = INFINITY, qmx = -INFINITY;
    if (t < C) {
        if (C == 256) {
            s  = Ss[t] + Ss[t + 256] + Ss[t + 512] + Ss[t + 768];
            mn = fminf(fminf(Sn[t], Sn[t + 256]), fminf(Sn[t + 512], Sn[t + 768]));
            mx = fmaxf(fmaxf(Sx[t], Sx[t + 256]), fmaxf(Sx[t + 512], Sx[t + 768]));
        } else { s = Ss[t]; mn = Sn[t]; mx = Sx[t]; }
        float mean = s / 12544.0f;
        float rng = mx - mn;
        float qg = fqv(gamma[t], gmn, gsc);
        float sg = qg / (rng * scale_fix + 1e-5f);
        mean_o[t] = mean; sg_o[t] = sg;
        float b3 = beta[t];
        float lo = (mn - mean) * sg + b3, hi = (mx - mean) * sg + b3;
        qmn = fminf(lo, hi); qmx = fmaxf(lo, hi);
    }
    __syncthreads();
    for (int o = 32; o; o >>= 1) { qmn = fminf(qmn, __shfl_down(qmn, o, 64)); qmx = fmaxf(qmx, __shfl_down(qmx, o, 64)); }
    if (lane == 0) { wr1[wv] = qmn; wr2[wv] = qmx; }
    __syncthreads();
    if (t == 0) {
        float a = INFINITY, b2 = -INFINITY;
        for (int i = 0; i < 16; i++) { a = fminf(a, wr1[i]); b2 = fmaxf(b2, wr2[i]); }
        qp[0] = a;
        qp[1] = fmaxf((b2 - a) / 255.0f, 1e-8f);
    }
}

// ---------------- final: out = fq(x) + fq(norm3(out3)) in place ----------------
__global__ __launch_bounds__(256) void k_final(const float* __restrict__ x, float* __restrict__ out,
                                               const float* __restrict__ mean, const float* __restrict__ sg,
                                               const float* __restrict__ beta, const float* __restrict__ sf,
                                               const float* __restrict__ qp) {
    float xmn = sf[8], xsc = sf[9];
    float qmn = qp[0], qsc = qp[1];
    const float4* xp = (const float4*)x;
    float4* yp = (float4*)out;
    int n4 = 12845056 / 4;
    int i = blockIdx.x * blockDim.x + threadIdx.x;
    int str = gridDim.x * blockDim.x;
    for (; i < n4; i += str) {
        int e = i * 4;
        int c = (e / 196) & 1023;
        float m = mean[c], s = sg[c], b = beta[c];
        float4 xv = xp[i], ov = yp[i], r;
        r.x = fqv(xv.x, xmn, xsc) + fqv((ov.x - m) * s + b, qmn, qsc);
        r.y = fqv(xv.y, xmn, xsc) + fqv((ov.y - m) * s + b, qmn, qsc);
        r.z = fqv(xv.z, xmn, xsc) + fqv((ov.z - m) * s + b, qmn, qsc);
        r.w = fqv(xv.w, xmn, xsc) + fqv((ov.w - m) * s + b, qmn, qsc);
        yp[i] = r;
    }
}

extern "C" void kernel_launch(void* const* d_in, const int* in_sizes, int n_in,
                              void* d_out, int out_size, void* d_ws, size_t ws_size,
                              hipStream_t stream) {
    const float* x  = (const float*)d_in[0];
    const float* w1 = (const float*)d_in[1];
    const float* g1 = (const float*)d_in[2];
    const float* b1 = (const float*)d_in[3];
    const float* w2 = (const float*)d_in[4];
    const float* g2 = (const float*)d_in[5];
    const float* b2 = (const float*)d_in[6];
    const float* w3 = (const float*)d_in[7];
    const float* g3 = (const float*)d_in[8];
    const float* b3 = (const float*)d_in[9];
    float* out = (float*)d_out;

    float* W = (float*)d_ws;
    float* OUT = W + OF_OUT;
    signed char* xc  = (signed char*)(W + OF_XC);
    signed char* z1p = (signed char*)(W + OF_Z1P);
    signed char* z2c = (signed char*)(W + OF_Z2C);
    signed char* wq1 = (signed char*)(W + OF_WQ1);
    signed char* wq2 = (signed char*)(W + OF_WQ2);
    signed char* wq3 = (signed char*)(W + OF_WQ3);
    float* R1 = W + OF_R1; float* R2 = W + OF_R2; float* R3 = W + OF_R3;
    float* T2 = W + OF_T2;
    float* CXp = W + OF_CXP; float* U2 = W + OF_U2; float* V2 = W + OF_V2; float* CZ = W + OF_CZ;
    float* P1s = W + OF_P1, *P1n = P1s + 50176, *P1x = P1s + 100352;
    float* P2s = W + OF_P2, *P2n = P2s + 50176, *P2x = P2s + 100352;
    float* P3s = W + OF_P3, *P3n = P3s + 100352, *P3x = P3s + 200704;
    float* Pmm = W + OF_PMM;
    float* S = W + OF_ST;
    float* MS = W + OF_MS;
    float* mean1 = MS, *sg1 = MS + 256, *mean2 = MS + 512, *sg2 = MS + 768, *mean3 = MS + 1024, *sg3 = MS + 2048;

    const float scale_fix =
        (float)((0.5 * 0.35) * (1.0 + sqrt(M_PI * log(4.0))) / sqrt(2.0 * log(12544.0)));

    // z1p border zeros (only remaining memset)
    hipMemsetAsync(z1p, 0, 4194304, stream);

    // fq params for x, w1, w2, w3 (two-phase, no atomics)
    k_minmax_all<<<1280, 256, 0, stream>>>((const float4*)x, (const float4*)w1,
                                           (const float4*)w2, (const float4*)w3, Pmm);
    k_fqparams2<<<1, 256, 0, stream>>>(Pmm, S);

    // weight codes + reductions (single launch)
    k_wcode_all<<<1536, 256, 0, stream>>>(w1, w2, w3, S, wq1, wq2, wq3, R1, R2, R3, T2);

    // x -> NHWC i8 codes + CX slice partials
    k_code0<<<dim3(7, 4, 64), 256, 0, stream>>>(x, xc, S + 8, CXp);

    // conv1 -> OUT NHWC + stage1 partials
    k_conv12<0><<<dim3(196, 4), 256, 0, stream>>>(xc, wq1, R1, nullptr, CXp, S + 11, S + 8, OUT, 1024,
                                                  P1s, P1n, P1x);
    k_finstats<<<1, 1024, 0, stream>>>(256, 196, g1, b1, P1s, P1n, P1x, mean1, sg1, S + 20, scale_fix);
    k_codeE<1><<<784, 256, 0, stream>>>(OUT, z1p, mean1, sg1, b1, S + 20, U2);
    k_v2<<<49, 256, 0, stream>>>(U2, V2);

    // conv2 -> OUT NHWC + stage2 partials
    k_conv12<1><<<dim3(196, 4), 256, 0, stream>>>(z1p, wq2, R2, T2, V2, S + 14, S + 20, OUT, 2304,
                                                  P2s, P2n, P2x);
    k_finstats<<<1, 1024, 0, stream>>>(256, 196, g2, b2, P2s, P2n, P2x, mean2, sg2, S + 23, scale_fix);
    k_codeE<0><<<784, 256, 0, stream>>>(OUT, z2c, mean2, sg2, b2, S + 23, CZ);

    // conv3 -> d_out NCHW (float4 stores) + stage3 partials
    k_conv3<<<dim3(98, 16), 256, 0, stream>>>(wq3, z2c, R3, CZ, S + 17, S + 23, out, P3s, P3n, P3x);
    k_finstats<<<1, 1024, 0, stream>>>(1024, 98, g3, b3, P3s, P3n, P3x, mean3, sg3, S + 26, scale_fix);
    k_final<<<2048, 256, 0, stream>>>(x, out, mean3, sg3, b3, S, S + 26);
}